// Round 5
// baseline (5849.159 us; speedup 1.0000x reference)
//
#include <hip/hip_runtime.h>
#include <math.h>

#define BB 8
#define NN 8192
#define SS 2048
#define KK 32
#define NP (BB*SS*KK)   /* 524288 points through the MLP */
#define EPSF 1e-5f
#define FG 4            /* blocks (CUs) per batch for FPS */

typedef float v2f __attribute__((ext_vector_type(2)));

// ---------------------------------------------------------------------------
// DPP-based wave64 max of a u64 key (dist_bits<<32 | ~p). Pure VALU.
// ---------------------------------------------------------------------------
template <int CTRL>
__device__ __forceinline__ unsigned long long dpp_max_step(unsigned long long key) {
    unsigned lo = (unsigned)key, hi = (unsigned)(key >> 32);
    unsigned nlo = (unsigned)__builtin_amdgcn_update_dpp((int)lo, (int)lo, CTRL, 0xf, 0xf, false);
    unsigned nhi = (unsigned)__builtin_amdgcn_update_dpp((int)hi, (int)hi, CTRL, 0xf, 0xf, false);
    unsigned long long nk = ((unsigned long long)nhi << 32) | nlo;
    return nk > key ? nk : key;
}

__device__ __forceinline__ unsigned long long wave_max_u64(unsigned long long key) {
    key = dpp_max_step<0x111>(key);  // row_shr:1
    key = dpp_max_step<0x112>(key);  // row_shr:2
    key = dpp_max_step<0x114>(key);  // row_shr:4
    key = dpp_max_step<0x118>(key);  // row_shr:8
    key = dpp_max_step<0x142>(key);  // row_bcast:15
    key = dpp_max_step<0x143>(key);  // row_bcast:31
    return key;                      // valid in lane 63
}

// ---------------------------------------------------------------------------
// FPS, multi-CU: 8 batches x FG=4 blocks, 512 threads each (cooperative
// launch -> co-residency guaranteed). Each block updates 2048 points
// (4/thread, packed-fp32 pairs), holds a FULL 128KB LDS coord copy for
// centroid lookup. Per iteration the 4 blocks of a batch exchange one u64
// key (dist_bits<<32 | ~global_p) through device-scope atomics:
//   publish: relaxed store comm[parity][slot], release store seq[slot]=it+1
//   consume: spin acquire seq[s] >= it+1 (monotone; max skew 1 iteration,
//            parity double-buffer makes the skew-1 overwrite safe)
// seq[] is zeroed by the on-stream memset every launch. Tie-break uses the
// GLOBAL point index -> bit-identical argmax sequence vs single-block.
// ---------------------------------------------------------------------------
__global__ __launch_bounds__(512) void fps_kernel(const float* __restrict__ xyz,
                                                  float* __restrict__ out_newxyz,
                                                  unsigned long long* __restrict__ comm,
                                                  unsigned* __restrict__ seqp) {
#pragma clang fp contract(off)
    const int T = 512;
    const int NPAIR = 2;             // 4 points per thread = 2 packed pairs
    int blk = blockIdx.x;
    int b = blk >> 2;                // batch
    int g = blk & (FG - 1);          // sub-block within batch
    int t = threadIdx.x;
    int wid  = t >> 6;
    int lane = t & 63;
    const float* x = xyz + b * NN * 3;
    float* nout = out_newxyz + b * SS * 3;
    int base = g * (NN / FG);        // this block's point range start
    int slot = b * FG + g;

    __shared__ float4 lxyz[NN];                       // 128 KB full coord copy
    __shared__ unsigned long long skey[2][8];         // parity wave keys
    __shared__ unsigned long long gkey[2][FG];        // parity peer keys

#pragma unroll
    for (int i = 0; i < NN / T; i++) {                // full cooperative fill
        int p = t + i * T;
        lxyz[p] = make_float4(x[p * 3 + 0], x[p * 3 + 1], x[p * 3 + 2], 0.f);
    }
    __syncthreads();

    v2f px2[NPAIR], py2[NPAIR], pz2[NPAIR], d2[NPAIR];
#pragma unroll
    for (int j = 0; j < NPAIR; j++) {
        int p0 = base + t + (2 * j) * T;
        int p1 = p0 + T;
        float4 a = lxyz[p0], c = lxyz[p1];
        px2[j].x = a.x; px2[j].y = c.x;
        py2[j].x = a.y; py2[j].y = c.y;
        pz2[j].x = a.z; pz2[j].y = c.z;
        d2[j].x = 1e10f; d2[j].y = 1e10f;
    }
    float4 c0 = lxyz[0];                              // far = 0 initially
    float cx = c0.x, cy = c0.y, cz = c0.z;

    for (int it = 0; it < SS; it++) {
        if (g == 0 && t == 0) {                        // record current far point
            nout[it * 3 + 0] = cx;
            nout[it * 3 + 1] = cy;
            nout[it * 3 + 2] = cz;
        }
        v2f cxx, cyy, czz;
        cxx.x = cx; cxx.y = cx;
        cyy.x = cy; cyy.y = cy;
        czz.x = cz; czz.y = cz;
        float lmax = -1.0f;
        int   li   = 0;
#pragma unroll
        for (int j = 0; j < NPAIR; j++) {
            v2f dx = px2[j] - cxx;
            v2f dy = py2[j] - cyy;
            v2f dz = pz2[j] - czz;
            v2f sx = dx * dx;
            v2f sy = dy * dy;
            v2f sz = dz * dz;
            v2f ss = (sx + sy) + sz;
            float e0 = fminf(d2[j].x, ss.x);
            float e1 = fminf(d2[j].y, ss.y);
            d2[j].x = e0;
            d2[j].y = e1;
            bool g0 = e0 > lmax;                       // strict: first wins
            lmax = g0 ? e0 : lmax;
            li   = g0 ? (2 * j) : li;
            bool g1 = e1 > lmax;
            lmax = g1 ? e1 : lmax;
            li   = g1 ? (2 * j + 1) : li;
        }
        int p = base + t + (li << 9);                  // GLOBAL point index
        unsigned long long key =
            ((unsigned long long)__float_as_uint(lmax) << 32) | (unsigned)(~p);
        key = wave_max_u64(key);                       // lane 63 holds wave max
        if (lane == 63) skey[it & 1][wid] = key;
        __syncthreads();
        if (t == 0) {                                  // block reduce + publish
            unsigned long long kb = skey[it & 1][0];
#pragma unroll
            for (int j = 1; j < 8; j++) {
                unsigned long long o = skey[it & 1][j];
                kb = (o > kb) ? o : kb;
            }
            __hip_atomic_store(&comm[(it & 1) * (BB * FG) + slot], kb,
                               __ATOMIC_RELAXED, __HIP_MEMORY_SCOPE_AGENT);
            __hip_atomic_store(&seqp[slot], (unsigned)(it + 1),
                               __ATOMIC_RELEASE, __HIP_MEMORY_SCOPE_AGENT);
        }
        if (t < FG) {                                  // gather the 4 peer keys
            int s = b * FG + t;
            while (__hip_atomic_load(&seqp[s], __ATOMIC_ACQUIRE,
                                     __HIP_MEMORY_SCOPE_AGENT) < (unsigned)(it + 1)) {}
            gkey[it & 1][t] = __hip_atomic_load(&comm[(it & 1) * (BB * FG) + s],
                                                __ATOMIC_RELAXED, __HIP_MEMORY_SCOPE_AGENT);
        }
        __syncthreads();
        unsigned long long k = gkey[it & 1][0];
#pragma unroll
        for (int j = 1; j < FG; j++) {
            unsigned long long o = gkey[it & 1][j];
            k = (o > k) ? o : k;
        }
        int gi = (int)(~(unsigned)k) & (NN - 1);
        float4 c = lxyz[gi];                           // broadcast ds_read_b128
        cx = c.x; cy = c.y; cz = c.z;
    }
}

// ---------------------------------------------------------------------------
// Ball query: one wave per query. Ordered compaction of first 32 in-radius
// indices (== reference's where->sort->truncate), pad with first index.
// ---------------------------------------------------------------------------
__global__ __launch_bounds__(256) void ballq_kernel(const float* __restrict__ xyz,
                                                    const float* __restrict__ new_xyz,
                                                    int* __restrict__ idx_out) {
    int q    = blockIdx.x * 4 + (threadIdx.x >> 6);
    int lane = threadIdx.x & 63;
    int b    = q >> 11;                        // q / SS
    const float* x = xyz + b * NN * 3;
    const float* c = new_xyz + q * 3;
    float cx = c[0], cy = c[1], cz = c[2];
    int* out = idx_out + q * KK;
    const float R2 = (float)(0.2 * 0.2);       // match reference double->f32 cast

    int count = 0;
    int first = -1;
    for (int base = 0; base < NN; base += 64) {
        int p = base + lane;
        float dx = __fsub_rn(x[p * 3 + 0], cx);
        float dy = __fsub_rn(x[p * 3 + 1], cy);
        float dz = __fsub_rn(x[p * 3 + 2], cz);
        float d  = __fadd_rn(__fadd_rn(__fmul_rn(dx, dx), __fmul_rn(dy, dy)),
                             __fmul_rn(dz, dz));
        bool in = !(d > R2);
        unsigned long long m = __ballot(in);
        if (first < 0 && m != 0ull) first = base + __ffsll((unsigned long long)m) - 1;
        int pre = __popcll(m & ((1ull << lane) - 1ull));
        int pos = count + pre;
        if (in && pos < KK) out[pos] = p;
        count += __popcll(m);
        if (count >= KK) break;                 // wave-uniform
    }
    for (int i2 = count + lane; i2 < KK; i2 += 64) out[i2] = first;
}

// ---------------------------------------------------------------------------
// MLP helpers (thread-per-point recompute chain; weights via uniform s_loads)
// ---------------------------------------------------------------------------
__device__ __forceinline__ void load_in6(const float* __restrict__ xyz,
                                         const float* __restrict__ points,
                                         const float* __restrict__ new_xyz,
                                         const int* __restrict__ idx, int p, float inx[6]) {
    int bs = p >> 5;
    int b  = bs >> 11;
    int pt = idx[p];
    const float* xb = xyz + ((long)b * NN + pt) * 3;
    const float* pb = points + ((long)b * NN + pt) * 3;
    const float* nx = new_xyz + bs * 3;
    inx[0] = xb[0] - nx[0];
    inx[1] = xb[1] - nx[1];
    inx[2] = xb[2] - nx[2];
    inx[3] = pb[0];
    inx[4] = pb[1];
    inx[5] = pb[2];
}

template <int CIN, int COUT>
__device__ __forceinline__ void linear(const float* __restrict__ w,
                                       const float* __restrict__ bias,
                                       const float* xin, float* yout) {
#pragma unroll
    for (int o = 0; o < COUT; o++) {
        float acc = bias[o];
#pragma unroll
        for (int j = 0; j < CIN; j++) acc = fmaf(w[o * CIN + j], xin[j], acc);
        yout[o] = acc;
    }
}

// compute per-channel BN scale/shift from raw sums (threads 0..C-1)
template <int C>
__device__ __forceinline__ void bn_coef(const float* __restrict__ stats,
                                        const float* __restrict__ g,
                                        const float* __restrict__ be,
                                        float* s_sc, float* s_sh) {
    int t = threadIdx.x;
    if (t < C) {
        float mean = stats[t] * (1.0f / (float)NP);
        float var  = stats[C + t] * (1.0f / (float)NP) - mean * mean;
        float rstd = 1.0f / sqrtf(var + EPSF);
        float sc = g[t] * rstd;
        s_sc[t] = sc;
        s_sh[t] = be[t] - mean * sc;
    }
    __syncthreads();
}

// block-level channel sums via LDS transpose (33.8KB), one atomic/chan/block
template <int C>
__device__ __forceinline__ void accum_stats(const float* y, float* __restrict__ gstats) {
    __shared__ float buf[256][33];
    int t = threadIdx.x;
#pragma unroll
    for (int h = 0; h < C / 32; h++) {
        __syncthreads();
#pragma unroll
        for (int c = 0; c < 32; c++) buf[t][c] = y[h * 32 + c];
        __syncthreads();
        if (t < 32) {
            float s = 0.f, sq = 0.f;
            for (int r = 0; r < 256; r++) {
                float v = buf[r][t];
                s += v;
                sq = fmaf(v, v, sq);
            }
            atomicAdd(&gstats[h * 32 + t], s);
            atomicAdd(&gstats[C + h * 32 + t], sq);
        }
    }
}

__global__ __launch_bounds__(256) void l0_stats_kernel(
    const float* __restrict__ xyz, const float* __restrict__ points,
    const float* __restrict__ new_xyz, const int* __restrict__ idx,
    const float* __restrict__ w0, const float* __restrict__ b0_,
    float* __restrict__ stats0) {
    int p = blockIdx.x * 256 + threadIdx.x;
    float inx[6];
    load_in6(xyz, points, new_xyz, idx, p, inx);
    float y0[32];
    linear<6, 32>(w0, b0_, inx, y0);
    accum_stats<32>(y0, stats0);
}

__global__ __launch_bounds__(256) void l1_stats_kernel(
    const float* __restrict__ xyz, const float* __restrict__ points,
    const float* __restrict__ new_xyz, const int* __restrict__ idx,
    const float* __restrict__ w0, const float* __restrict__ b0_,
    const float* __restrict__ g0, const float* __restrict__ be0,
    const float* __restrict__ w1, const float* __restrict__ b1_,
    const float* __restrict__ stats0, float* __restrict__ stats1) {
    __shared__ float sc0[32], sh0[32];
    bn_coef<32>(stats0, g0, be0, sc0, sh0);
    int p = blockIdx.x * 256 + threadIdx.x;
    float inx[6];
    load_in6(xyz, points, new_xyz, idx, p, inx);
    float y0[32];
    linear<6, 32>(w0, b0_, inx, y0);
#pragma unroll
    for (int c = 0; c < 32; c++) y0[c] = fmaxf(fmaf(y0[c], sc0[c], sh0[c]), 0.f);
    float y1[32];
    linear<32, 32>(w1, b1_, y0, y1);
    accum_stats<32>(y1, stats1);
}

__global__ __launch_bounds__(256) void l2_stats_kernel(
    const float* __restrict__ xyz, const float* __restrict__ points,
    const float* __restrict__ new_xyz, const int* __restrict__ idx,
    const float* __restrict__ w0, const float* __restrict__ b0_,
    const float* __restrict__ g0, const float* __restrict__ be0,
    const float* __restrict__ w1, const float* __restrict__ b1_,
    const float* __restrict__ g1, const float* __restrict__ be1,
    const float* __restrict__ w2, const float* __restrict__ b2_,
    const float* __restrict__ stats0, const float* __restrict__ stats1,
    float* __restrict__ stats2) {
    __shared__ float sc0[32], sh0[32], sc1[32], sh1[32];
    bn_coef<32>(stats0, g0, be0, sc0, sh0);
    bn_coef<32>(stats1, g1, be1, sc1, sh1);
    int p = blockIdx.x * 256 + threadIdx.x;
    float inx[6];
    load_in6(xyz, points, new_xyz, idx, p, inx);
    float y0[32];
    linear<6, 32>(w0, b0_, inx, y0);
#pragma unroll
    for (int c = 0; c < 32; c++) y0[c] = fmaxf(fmaf(y0[c], sc0[c], sh0[c]), 0.f);
    float y1[32];
    linear<32, 32>(w1, b1_, y0, y1);
#pragma unroll
    for (int c = 0; c < 32; c++) y1[c] = fmaxf(fmaf(y1[c], sc1[c], sh1[c]), 0.f);
    float y2[64];
    linear<32, 64>(w2, b2_, y1, y2);
    accum_stats<64>(y2, stats2);
}

__global__ __launch_bounds__(256) void final_kernel(
    const float* __restrict__ xyz, const float* __restrict__ points,
    const float* __restrict__ new_xyz, const int* __restrict__ idx,
    const float* __restrict__ w0, const float* __restrict__ b0_,
    const float* __restrict__ g0, const float* __restrict__ be0,
    const float* __restrict__ w1, const float* __restrict__ b1_,
    const float* __restrict__ g1, const float* __restrict__ be1,
    const float* __restrict__ w2, const float* __restrict__ b2_,
    const float* __restrict__ g2, const float* __restrict__ be2,
    const float* __restrict__ stats0, const float* __restrict__ stats1,
    const float* __restrict__ stats2, float* __restrict__ out_points) {
    __shared__ float sc0[32], sh0[32], sc1[32], sh1[32], sc2[64], sh2[64];
    bn_coef<32>(stats0, g0, be0, sc0, sh0);
    bn_coef<32>(stats1, g1, be1, sc1, sh1);
    bn_coef<64>(stats2, g2, be2, sc2, sh2);
    int p = blockIdx.x * 256 + threadIdx.x;
    float inx[6];
    load_in6(xyz, points, new_xyz, idx, p, inx);
    float y0[32];
    linear<6, 32>(w0, b0_, inx, y0);
#pragma unroll
    for (int c = 0; c < 32; c++) y0[c] = fmaxf(fmaf(y0[c], sc0[c], sh0[c]), 0.f);
    float y1[32];
    linear<32, 32>(w1, b1_, y0, y1);
#pragma unroll
    for (int c = 0; c < 32; c++) y1[c] = fmaxf(fmaf(y1[c], sc1[c], sh1[c]), 0.f);
    float y2[64];
    linear<32, 64>(w2, b2_, y1, y2);
    // BN + relu + max over k (k == lane&31; butterfly within each 32-lane half)
#pragma unroll
    for (int c = 0; c < 64; c++) {
        float v = fmaxf(fmaf(y2[c], sc2[c], sh2[c]), 0.f);
#pragma unroll
        for (int off = 1; off < 32; off <<= 1)
            v = fmaxf(v, __shfl_xor(v, off));
        y2[c] = v;
    }
    int lane = threadIdx.x & 63;
    if ((lane & 31) == 0) {                     // k == 0 lanes write their (b,s) row
        int bs = p >> 5;
        float4* o = (float4*)(out_points + (long)bs * 64);
#pragma unroll
        for (int c4 = 0; c4 < 16; c4++)
            o[c4] = make_float4(y2[c4 * 4], y2[c4 * 4 + 1], y2[c4 * 4 + 2], y2[c4 * 4 + 3]);
    }
}

// ---------------------------------------------------------------------------
extern "C" void kernel_launch(void* const* d_in, const int* in_sizes, int n_in,
                              void* d_out, int out_size, void* d_ws, size_t ws_size,
                              hipStream_t stream) {
    (void)in_sizes; (void)n_in; (void)out_size; (void)ws_size;
    const float* xyz    = (const float*)d_in[0];
    const float* points = (const float*)d_in[1];
    const float* w0  = (const float*)d_in[2];
    const float* b0_ = (const float*)d_in[3];
    const float* g0  = (const float*)d_in[4];
    const float* be0 = (const float*)d_in[5];
    const float* w1  = (const float*)d_in[6];
    const float* b1_ = (const float*)d_in[7];
    const float* g1  = (const float*)d_in[8];
    const float* be1 = (const float*)d_in[9];
    const float* w2  = (const float*)d_in[10];
    const float* b2_ = (const float*)d_in[11];
    const float* g2  = (const float*)d_in[12];
    const float* be2 = (const float*)d_in[13];

    float* out        = (float*)d_out;
    float* out_newxyz = out;                 // (8,2048,3)
    float* out_points = out + BB * SS * 3;   // (8,2048,64)

    int*   idx    = (int*)d_ws;              // NP ints = 2MB
    float* stats  = (float*)d_ws + NP;       // 256 floats
    float* stats0 = stats;
    float* stats1 = stats + 64;
    float* stats2 = stats + 128;
    unsigned long long* comm = (unsigned long long*)((char*)d_ws + (size_t)NP * 4 + 1024);
    unsigned* seqp = (unsigned*)(comm + 2 * BB * FG);   // 64 u64 then 32 u32

    // zero stats (1024B) + comm (512B) + seq (128B) in one shot
    hipMemsetAsync(stats, 0, 1024 + 512 + 128, stream);

    {
        void* args[] = { (void*)&xyz, (void*)&out_newxyz, (void*)&comm, (void*)&seqp };
        hipLaunchCooperativeKernel((const void*)fps_kernel, dim3(BB * FG), dim3(512),
                                   args, 0, stream);
    }
    ballq_kernel<<<BB * SS / 4, 256, 0, stream>>>(xyz, out_newxyz, idx);
    l0_stats_kernel<<<NP / 256, 256, 0, stream>>>(xyz, points, out_newxyz, idx, w0, b0_, stats0);
    l1_stats_kernel<<<NP / 256, 256, 0, stream>>>(xyz, points, out_newxyz, idx,
                                                  w0, b0_, g0, be0, w1, b1_, stats0, stats1);
    l2_stats_kernel<<<NP / 256, 256, 0, stream>>>(xyz, points, out_newxyz, idx,
                                                  w0, b0_, g0, be0, w1, b1_, g1, be1,
                                                  w2, b2_, stats0, stats1, stats2);
    final_kernel<<<NP / 256, 256, 0, stream>>>(xyz, points, out_newxyz, idx,
                                               w0, b0_, g0, be0, w1, b1_, g1, be1,
                                               w2, b2_, g2, be2, stats0, stats1, stats2,
                                               out_points);
}

// Round 6
// 2928.029 us; speedup vs baseline: 1.9976x; 1.9976x over previous
//
#include <hip/hip_runtime.h>
#include <math.h>

#define BB 8
#define NN 8192
#define SS 2048
#define KK 32
#define NP (BB*SS*KK)   /* 524288 points through the MLP */
#define EPSF 1e-5f
#define TT 1024         /* fps threads per block */

typedef float v2f __attribute__((ext_vector_type(2)));

// ---------------------------------------------------------------------------
// DPP-based wave64 max of a u64 key (dist_bits<<32 | ~p). Pure VALU.
// ---------------------------------------------------------------------------
template <int CTRL>
__device__ __forceinline__ unsigned long long dpp_max_step(unsigned long long key) {
    unsigned lo = (unsigned)key, hi = (unsigned)(key >> 32);
    unsigned nlo = (unsigned)__builtin_amdgcn_update_dpp((int)lo, (int)lo, CTRL, 0xf, 0xf, false);
    unsigned nhi = (unsigned)__builtin_amdgcn_update_dpp((int)hi, (int)hi, CTRL, 0xf, 0xf, false);
    unsigned long long nk = ((unsigned long long)nhi << 32) | nlo;
    return nk > key ? nk : key;
}

__device__ __forceinline__ unsigned long long wave_max_u64(unsigned long long key) {
    key = dpp_max_step<0x111>(key);  // row_shr:1
    key = dpp_max_step<0x112>(key);  // row_shr:2
    key = dpp_max_step<0x114>(key);  // row_shr:4
    key = dpp_max_step<0x118>(key);  // row_shr:8
    key = dpp_max_step<0x142>(key);  // row_bcast:15
    key = dpp_max_step<0x143>(key);  // row_bcast:31
    return key;                      // valid in lane 63
}

// ---------------------------------------------------------------------------
// FPS: one block per batch (cross-workgroup exchange measured at ~2.5us/iter
// in R4 -> single-CU per batch is structural). 1024 threads (16 waves ->
// 4 waves/SIMD to pipeline the reduction tail), 8 points/thread.
// Inner loop is pure packed fp32: pk_sub/mul/add + pk_min(dist) +
// pk_max(running max) = 5 insts/point; argmax slot resolved AFTER the loop
// (scan high->low slot => smallest index among ties, matching np.argmax).
// u64 key (dist_bits<<32 | ~p) -> DPP wave max -> parity LDS slots ->
// 16-slot scan -> centroid from full 128KB LDS float4 copy.
// Bit-exact: contract(off), ((dx*dx+dy*dy)+dz*dz), exact coord copies.
// ---------------------------------------------------------------------------
__global__ __launch_bounds__(1024) void fps_kernel(const float* __restrict__ xyz,
                                                   float* __restrict__ out_newxyz) {
#pragma clang fp contract(off)
    const int PPT = NN / TT;         // 8 points per thread
    const int NPAIR = PPT / 2;       // 4 packed pairs
    int b = blockIdx.x;
    int t = threadIdx.x;
    int wid  = t >> 6;               // 0..15
    int lane = t & 63;
    const float* x = xyz + b * NN * 3;
    float* nout = out_newxyz + b * SS * 3;

    __shared__ float4 lxyz[NN];                       // 128 KB coord copy
    __shared__ unsigned long long skey[2][16];        // parity-buffered wave keys

    v2f px2[NPAIR], py2[NPAIR], pz2[NPAIR], d2[NPAIR];
#pragma unroll
    for (int j = 0; j < NPAIR; j++) {
        int p0 = t + (2 * j) * TT;                    // slot 2j
        int p1 = p0 + TT;                             // slot 2j+1
        float ax = x[p0 * 3 + 0], ay = x[p0 * 3 + 1], az = x[p0 * 3 + 2];
        float bx = x[p1 * 3 + 0], by = x[p1 * 3 + 1], bz = x[p1 * 3 + 2];
        px2[j].x = ax; px2[j].y = bx;
        py2[j].x = ay; py2[j].y = by;
        pz2[j].x = az; pz2[j].y = bz;
        lxyz[p0] = make_float4(ax, ay, az, 0.f);
        lxyz[p1] = make_float4(bx, by, bz, 0.f);
        d2[j].x = 1e10f; d2[j].y = 1e10f;
    }
    __syncthreads();
    float4 c0 = lxyz[0];                              // far = 0 initially
    float cx = c0.x, cy = c0.y, cz = c0.z;

    for (int it = 0; it < SS; it++) {
        if (t == 0) {                                  // record current far point
            nout[it * 3 + 0] = cx;
            nout[it * 3 + 1] = cy;
            nout[it * 3 + 2] = cz;
        }
        v2f cxx, cyy, czz;
        cxx.x = cx; cxx.y = cx;
        cyy.x = cy; cyy.y = cy;
        czz.x = cz; czz.y = cz;
        // pure packed update; argmax resolution deferred
        v2f vmax;
        vmax.x = -1.0f; vmax.y = -1.0f;
#pragma unroll
        for (int j = 0; j < NPAIR; j++) {
            v2f dx = px2[j] - cxx;                     // v_pk_add_f32 (neg)
            v2f dy = py2[j] - cyy;
            v2f dz = pz2[j] - czz;
            v2f ss = (dx * dx + dy * dy) + dz * dz;    // pk_mul/pk_add
            v2f e  = __builtin_elementwise_min(d2[j], ss);   // v_pk_min_f32
            d2[j] = e;
            vmax = __builtin_elementwise_max(vmax, e);       // v_pk_max_f32
        }
        float lmax = fmaxf(vmax.x, vmax.y);
        // resolve smallest slot attaining lmax (high->low so low overwrites;
        // within pair .x (slot 2j) after .y (slot 2j+1))
        int li = 0;
#pragma unroll
        for (int j = NPAIR - 1; j >= 0; j--) {
            li = (d2[j].y == lmax) ? (2 * j + 1) : li;
            li = (d2[j].x == lmax) ? (2 * j)     : li;
        }
        int p = t + li * TT;                           // global point index
        unsigned long long key =
            ((unsigned long long)__float_as_uint(lmax) << 32) | (unsigned)(~p);
        key = wave_max_u64(key);                       // DPP, valid in lane 63
        if (lane == 63) skey[it & 1][wid] = key;
        __syncthreads();
        unsigned long long k = skey[it & 1][0];
#pragma unroll
        for (int j = 1; j < 16; j++) {
            unsigned long long o = skey[it & 1][j];
            k = (o > k) ? o : k;
        }
        int gi = (int)(~(unsigned)k) & (NN - 1);
        float4 c = lxyz[gi];                           // one broadcast ds_read_b128
        cx = c.x; cy = c.y; cz = c.z;
    }
}

// ---------------------------------------------------------------------------
// Ball query: one wave per query. Ordered compaction of first 32 in-radius
// indices (== reference's where->sort->truncate), pad with first index.
// ---------------------------------------------------------------------------
__global__ __launch_bounds__(256) void ballq_kernel(const float* __restrict__ xyz,
                                                    const float* __restrict__ new_xyz,
                                                    int* __restrict__ idx_out) {
    int q    = blockIdx.x * 4 + (threadIdx.x >> 6);
    int lane = threadIdx.x & 63;
    int b    = q >> 11;                        // q / SS
    const float* x = xyz + b * NN * 3;
    const float* c = new_xyz + q * 3;
    float cx = c[0], cy = c[1], cz = c[2];
    int* out = idx_out + q * KK;
    const float R2 = (float)(0.2 * 0.2);       // match reference double->f32 cast

    int count = 0;
    int first = -1;
    for (int base = 0; base < NN; base += 64) {
        int p = base + lane;
        float dx = __fsub_rn(x[p * 3 + 0], cx);
        float dy = __fsub_rn(x[p * 3 + 1], cy);
        float dz = __fsub_rn(x[p * 3 + 2], cz);
        float d  = __fadd_rn(__fadd_rn(__fmul_rn(dx, dx), __fmul_rn(dy, dy)),
                             __fmul_rn(dz, dz));
        bool in = !(d > R2);
        unsigned long long m = __ballot(in);
        if (first < 0 && m != 0ull) first = base + __ffsll((unsigned long long)m) - 1;
        int pre = __popcll(m & ((1ull << lane) - 1ull));
        int pos = count + pre;
        if (in && pos < KK) out[pos] = p;
        count += __popcll(m);
        if (count >= KK) break;                 // wave-uniform
    }
    for (int i2 = count + lane; i2 < KK; i2 += 64) out[i2] = first;
}

// ---------------------------------------------------------------------------
// MLP helpers (thread-per-point recompute chain; weights via uniform s_loads)
// ---------------------------------------------------------------------------
__device__ __forceinline__ void load_in6(const float* __restrict__ xyz,
                                         const float* __restrict__ points,
                                         const float* __restrict__ new_xyz,
                                         const int* __restrict__ idx, int p, float inx[6]) {
    int bs = p >> 5;
    int b  = bs >> 11;
    int pt = idx[p];
    const float* xb = xyz + ((long)b * NN + pt) * 3;
    const float* pb = points + ((long)b * NN + pt) * 3;
    const float* nx = new_xyz + bs * 3;
    inx[0] = xb[0] - nx[0];
    inx[1] = xb[1] - nx[1];
    inx[2] = xb[2] - nx[2];
    inx[3] = pb[0];
    inx[4] = pb[1];
    inx[5] = pb[2];
}

template <int CIN, int COUT>
__device__ __forceinline__ void linear(const float* __restrict__ w,
                                       const float* __restrict__ bias,
                                       const float* xin, float* yout) {
#pragma unroll
    for (int o = 0; o < COUT; o++) {
        float acc = bias[o];
#pragma unroll
        for (int j = 0; j < CIN; j++) acc = fmaf(w[o * CIN + j], xin[j], acc);
        yout[o] = acc;
    }
}

// compute per-channel BN scale/shift from raw sums (threads 0..C-1)
template <int C>
__device__ __forceinline__ void bn_coef(const float* __restrict__ stats,
                                        const float* __restrict__ g,
                                        const float* __restrict__ be,
                                        float* s_sc, float* s_sh) {
    int t = threadIdx.x;
    if (t < C) {
        float mean = stats[t] * (1.0f / (float)NP);
        float var  = stats[C + t] * (1.0f / (float)NP) - mean * mean;
        float rstd = 1.0f / sqrtf(var + EPSF);
        float sc = g[t] * rstd;
        s_sc[t] = sc;
        s_sh[t] = be[t] - mean * sc;
    }
    __syncthreads();
}

// block-level channel sums via LDS transpose (33.8KB), one atomic/chan/block
template <int C>
__device__ __forceinline__ void accum_stats(const float* y, float* __restrict__ gstats) {
    __shared__ float buf[256][33];
    int t = threadIdx.x;
#pragma unroll
    for (int h = 0; h < C / 32; h++) {
        __syncthreads();
#pragma unroll
        for (int c = 0; c < 32; c++) buf[t][c] = y[h * 32 + c];
        __syncthreads();
        if (t < 32) {
            float s = 0.f, sq = 0.f;
            for (int r = 0; r < 256; r++) {
                float v = buf[r][t];
                s += v;
                sq = fmaf(v, v, sq);
            }
            atomicAdd(&gstats[h * 32 + t], s);
            atomicAdd(&gstats[C + h * 32 + t], sq);
        }
    }
}

__global__ __launch_bounds__(256) void l0_stats_kernel(
    const float* __restrict__ xyz, const float* __restrict__ points,
    const float* __restrict__ new_xyz, const int* __restrict__ idx,
    const float* __restrict__ w0, const float* __restrict__ b0_,
    float* __restrict__ stats0) {
    int p = blockIdx.x * 256 + threadIdx.x;
    float inx[6];
    load_in6(xyz, points, new_xyz, idx, p, inx);
    float y0[32];
    linear<6, 32>(w0, b0_, inx, y0);
    accum_stats<32>(y0, stats0);
}

__global__ __launch_bounds__(256) void l1_stats_kernel(
    const float* __restrict__ xyz, const float* __restrict__ points,
    const float* __restrict__ new_xyz, const int* __restrict__ idx,
    const float* __restrict__ w0, const float* __restrict__ b0_,
    const float* __restrict__ g0, const float* __restrict__ be0,
    const float* __restrict__ w1, const float* __restrict__ b1_,
    const float* __restrict__ stats0, float* __restrict__ stats1) {
    __shared__ float sc0[32], sh0[32];
    bn_coef<32>(stats0, g0, be0, sc0, sh0);
    int p = blockIdx.x * 256 + threadIdx.x;
    float inx[6];
    load_in6(xyz, points, new_xyz, idx, p, inx);
    float y0[32];
    linear<6, 32>(w0, b0_, inx, y0);
#pragma unroll
    for (int c = 0; c < 32; c++) y0[c] = fmaxf(fmaf(y0[c], sc0[c], sh0[c]), 0.f);
    float y1[32];
    linear<32, 32>(w1, b1_, y0, y1);
    accum_stats<32>(y1, stats1);
}

__global__ __launch_bounds__(256) void l2_stats_kernel(
    const float* __restrict__ xyz, const float* __restrict__ points,
    const float* __restrict__ new_xyz, const int* __restrict__ idx,
    const float* __restrict__ w0, const float* __restrict__ b0_,
    const float* __restrict__ g0, const float* __restrict__ be0,
    const float* __restrict__ w1, const float* __restrict__ b1_,
    const float* __restrict__ g1, const float* __restrict__ be1,
    const float* __restrict__ w2, const float* __restrict__ b2_,
    const float* __restrict__ stats0, const float* __restrict__ stats1,
    float* __restrict__ stats2) {
    __shared__ float sc0[32], sh0[32], sc1[32], sh1[32];
    bn_coef<32>(stats0, g0, be0, sc0, sh0);
    bn_coef<32>(stats1, g1, be1, sc1, sh1);
    int p = blockIdx.x * 256 + threadIdx.x;
    float inx[6];
    load_in6(xyz, points, new_xyz, idx, p, inx);
    float y0[32];
    linear<6, 32>(w0, b0_, inx, y0);
#pragma unroll
    for (int c = 0; c < 32; c++) y0[c] = fmaxf(fmaf(y0[c], sc0[c], sh0[c]), 0.f);
    float y1[32];
    linear<32, 32>(w1, b1_, y0, y1);
#pragma unroll
    for (int c = 0; c < 32; c++) y1[c] = fmaxf(fmaf(y1[c], sc1[c], sh1[c]), 0.f);
    float y2[64];
    linear<32, 64>(w2, b2_, y1, y2);
    accum_stats<64>(y2, stats2);
}

__global__ __launch_bounds__(256) void final_kernel(
    const float* __restrict__ xyz, const float* __restrict__ points,
    const float* __restrict__ new_xyz, const int* __restrict__ idx,
    const float* __restrict__ w0, const float* __restrict__ b0_,
    const float* __restrict__ g0, const float* __restrict__ be0,
    const float* __restrict__ w1, const float* __restrict__ b1_,
    const float* __restrict__ g1, const float* __restrict__ be1,
    const float* __restrict__ w2, const float* __restrict__ b2_,
    const float* __restrict__ g2, const float* __restrict__ be2,
    const float* __restrict__ stats0, const float* __restrict__ stats1,
    const float* __restrict__ stats2, float* __restrict__ out_points) {
    __shared__ float sc0[32], sh0[32], sc1[32], sh1[32], sc2[64], sh2[64];
    bn_coef<32>(stats0, g0, be0, sc0, sh0);
    bn_coef<32>(stats1, g1, be1, sc1, sh1);
    bn_coef<64>(stats2, g2, be2, sc2, sh2);
    int p = blockIdx.x * 256 + threadIdx.x;
    float inx[6];
    load_in6(xyz, points, new_xyz, idx, p, inx);
    float y0[32];
    linear<6, 32>(w0, b0_, inx, y0);
#pragma unroll
    for (int c = 0; c < 32; c++) y0[c] = fmaxf(fmaf(y0[c], sc0[c], sh0[c]), 0.f);
    float y1[32];
    linear<32, 32>(w1, b1_, y0, y1);
#pragma unroll
    for (int c = 0; c < 32; c++) y1[c] = fmaxf(fmaf(y1[c], sc1[c], sh1[c]), 0.f);
    float y2[64];
    linear<32, 64>(w2, b2_, y1, y2);
    // BN + relu + max over k (k == lane&31; butterfly within each 32-lane half)
#pragma unroll
    for (int c = 0; c < 64; c++) {
        float v = fmaxf(fmaf(y2[c], sc2[c], sh2[c]), 0.f);
#pragma unroll
        for (int off = 1; off < 32; off <<= 1)
            v = fmaxf(v, __shfl_xor(v, off));
        y2[c] = v;
    }
    int lane = threadIdx.x & 63;
    if ((lane & 31) == 0) {                     // k == 0 lanes write their (b,s) row
        int bs = p >> 5;
        float4* o = (float4*)(out_points + (long)bs * 64);
#pragma unroll
        for (int c4 = 0; c4 < 16; c4++)
            o[c4] = make_float4(y2[c4 * 4], y2[c4 * 4 + 1], y2[c4 * 4 + 2], y2[c4 * 4 + 3]);
    }
}

// ---------------------------------------------------------------------------
extern "C" void kernel_launch(void* const* d_in, const int* in_sizes, int n_in,
                              void* d_out, int out_size, void* d_ws, size_t ws_size,
                              hipStream_t stream) {
    (void)in_sizes; (void)n_in; (void)out_size; (void)ws_size;
    const float* xyz    = (const float*)d_in[0];
    const float* points = (const float*)d_in[1];
    const float* w0  = (const float*)d_in[2];
    const float* b0_ = (const float*)d_in[3];
    const float* g0  = (const float*)d_in[4];
    const float* be0 = (const float*)d_in[5];
    const float* w1  = (const float*)d_in[6];
    const float* b1_ = (const float*)d_in[7];
    const float* g1  = (const float*)d_in[8];
    const float* be1 = (const float*)d_in[9];
    const float* w2  = (const float*)d_in[10];
    const float* b2_ = (const float*)d_in[11];
    const float* g2  = (const float*)d_in[12];
    const float* be2 = (const float*)d_in[13];

    float* out        = (float*)d_out;
    float* out_newxyz = out;                 // (8,2048,3)
    float* out_points = out + BB * SS * 3;   // (8,2048,64)

    int*   idx    = (int*)d_ws;              // NP ints = 2MB
    float* stats  = (float*)d_ws + NP;
    float* stats0 = stats;                   // 64 floats (sum32+sq32)
    float* stats1 = stats + 64;              // 64 floats
    float* stats2 = stats + 128;             // 128 floats (sum64+sq64)

    hipMemsetAsync(stats, 0, 256 * sizeof(float), stream);

    fps_kernel<<<BB, TT, 0, stream>>>(xyz, out_newxyz);
    ballq_kernel<<<BB * SS / 4, 256, 0, stream>>>(xyz, out_newxyz, idx);
    l0_stats_kernel<<<NP / 256, 256, 0, stream>>>(xyz, points, out_newxyz, idx, w0, b0_, stats0);
    l1_stats_kernel<<<NP / 256, 256, 0, stream>>>(xyz, points, out_newxyz, idx,
                                                  w0, b0_, g0, be0, w1, b1_, stats0, stats1);
    l2_stats_kernel<<<NP / 256, 256, 0, stream>>>(xyz, points, out_newxyz, idx,
                                                  w0, b0_, g0, be0, w1, b1_, g1, be1,
                                                  w2, b2_, stats0, stats1, stats2);
    final_kernel<<<NP / 256, 256, 0, stream>>>(xyz, points, out_newxyz, idx,
                                               w0, b0_, g0, be0, w1, b1_, g1, be1,
                                               w2, b2_, g2, be2, stats0, stats1, stats2,
                                               out_points);
}

// Round 7
// 2311.169 us; speedup vs baseline: 2.5308x; 1.2669x over previous
//
#include <hip/hip_runtime.h>
#include <math.h>

#define BB 8
#define NN 8192
#define SS 2048
#define KK 32
#define NP (BB*SS*KK)   /* 524288 points through the MLP */
#define EPSF 1e-5f
#define TT 256          /* fps threads per block: W=1 wave/SIMD (R6 model: per-wave overhead f~300 insts dominates; minimize waves) */

typedef float v2f __attribute__((ext_vector_type(2)));

// ---------------------------------------------------------------------------
// DPP-based wave64 max of a u64 key (dist_bits<<32 | ~p). Pure VALU.
// ---------------------------------------------------------------------------
template <int CTRL>
__device__ __forceinline__ unsigned long long dpp_max_step(unsigned long long key) {
    unsigned lo = (unsigned)key, hi = (unsigned)(key >> 32);
    unsigned nlo = (unsigned)__builtin_amdgcn_update_dpp((int)lo, (int)lo, CTRL, 0xf, 0xf, false);
    unsigned nhi = (unsigned)__builtin_amdgcn_update_dpp((int)hi, (int)hi, CTRL, 0xf, 0xf, false);
    unsigned long long nk = ((unsigned long long)nhi << 32) | nlo;
    return nk > key ? nk : key;
}

__device__ __forceinline__ unsigned long long wave_max_u64(unsigned long long key) {
    key = dpp_max_step<0x111>(key);  // row_shr:1
    key = dpp_max_step<0x112>(key);  // row_shr:2
    key = dpp_max_step<0x114>(key);  // row_shr:4
    key = dpp_max_step<0x118>(key);  // row_shr:8
    key = dpp_max_step<0x142>(key);  // row_bcast:15
    key = dpp_max_step<0x143>(key);  // row_bcast:31
    return key;                      // valid in lane 63
}

// ---------------------------------------------------------------------------
// FPS: one block per batch (R4 measured cross-WG exchange at ~2.5us/iter ->
// single-CU per batch is structural). 256 threads = 1 wave/SIMD: the
// R3(512thr)/R5(1024thr) pair fits issue/SIMD = (192 + ~300*W)*2cyc, i.e.
// per-wave fixed overhead (DPP+resolve+scan+marshalling) dominates ->
// minimize W. 32 points/thread, pure packed-fp32 inner loop (no in-loop
// tracking), post-loop argmax resolve (scan high->low slot => smallest
// index among ties == np.argmax), u64 key -> DPP wave max -> 4-key LDS
// scan (2x ds_read_b128) -> centroid from 128KB LDS float4 copy.
// Bit-exact: contract(off), ((dx*dx+dy*dy)+dz*dz), exact coord copies.
// ---------------------------------------------------------------------------
__global__ __launch_bounds__(TT) void fps_kernel(const float* __restrict__ xyz,
                                                 float* __restrict__ out_newxyz) {
#pragma clang fp contract(off)
    const int PPT = NN / TT;         // 32 points per thread
    const int NPAIR = PPT / 2;       // 16 packed pairs
    int b = blockIdx.x;
    int t = threadIdx.x;
    int wid  = t >> 6;               // 0..3
    int lane = t & 63;
    const float* x = xyz + b * NN * 3;
    float* nout = out_newxyz + b * SS * 3;

    __shared__ float4 lxyz[NN];                            // 128 KB coord copy
    __shared__ __align__(16) unsigned long long skey[2][4]; // parity wave keys

    v2f px2[NPAIR], py2[NPAIR], pz2[NPAIR], d2[NPAIR];
#pragma unroll
    for (int j = 0; j < NPAIR; j++) {
        int p0 = t + (2 * j) * TT;                    // slot 2j
        int p1 = p0 + TT;                             // slot 2j+1
        float ax = x[p0 * 3 + 0], ay = x[p0 * 3 + 1], az = x[p0 * 3 + 2];
        float bx = x[p1 * 3 + 0], by = x[p1 * 3 + 1], bz = x[p1 * 3 + 2];
        px2[j].x = ax; px2[j].y = bx;
        py2[j].x = ay; py2[j].y = by;
        pz2[j].x = az; pz2[j].y = bz;
        lxyz[p0] = make_float4(ax, ay, az, 0.f);
        lxyz[p1] = make_float4(bx, by, bz, 0.f);
        d2[j].x = 1e10f; d2[j].y = 1e10f;
    }
    __syncthreads();
    float4 c0 = lxyz[0];                              // far = 0 initially
    float cx = c0.x, cy = c0.y, cz = c0.z;

    for (int it = 0; it < SS; it++) {
        if (t == 0) {                                  // record current far point
            nout[it * 3 + 0] = cx;
            nout[it * 3 + 1] = cy;
            nout[it * 3 + 2] = cz;
        }
        v2f cxx, cyy, czz;
        cxx.x = cx; cxx.y = cx;
        cyy.x = cy; cyy.y = cy;
        czz.x = cz; czz.y = cz;
        // pure packed update; argmax resolution deferred
        v2f vmax;
        vmax.x = -1.0f; vmax.y = -1.0f;
#pragma unroll
        for (int j = 0; j < NPAIR; j++) {
            v2f dx = px2[j] - cxx;
            v2f dy = py2[j] - cyy;
            v2f dz = pz2[j] - czz;
            v2f ss = (dx * dx + dy * dy) + dz * dz;
            v2f e  = __builtin_elementwise_min(d2[j], ss);
            d2[j] = e;
            vmax = __builtin_elementwise_max(vmax, e);
        }
        float lmax = fmaxf(vmax.x, vmax.y);
        // resolve smallest slot attaining lmax (high->low so low overwrites;
        // within pair .x (slot 2j) after .y (slot 2j+1))
        int li = 0;
#pragma unroll
        for (int j = NPAIR - 1; j >= 0; j--) {
            li = (d2[j].y == lmax) ? (2 * j + 1) : li;
            li = (d2[j].x == lmax) ? (2 * j)     : li;
        }
        int p = t + li * TT;                           // global point index
        unsigned long long key =
            ((unsigned long long)__float_as_uint(lmax) << 32) | (unsigned)(~p);
        key = wave_max_u64(key);                       // DPP, valid in lane 63
        if (lane == 63) skey[it & 1][wid] = key;
        __syncthreads();
        const ulonglong2* sk = (const ulonglong2*)&skey[it & 1][0];
        ulonglong2 ab = sk[0];                         // 2x ds_read_b128
        ulonglong2 cd = sk[1];
        unsigned long long k = ab.x;
        k = (ab.y > k) ? ab.y : k;
        k = (cd.x > k) ? cd.x : k;
        k = (cd.y > k) ? cd.y : k;
        int gi = (int)(~(unsigned)k) & (NN - 1);
        float4 c = lxyz[gi];                           // one broadcast ds_read_b128
        cx = c.x; cy = c.y; cz = c.z;
    }
}

// ---------------------------------------------------------------------------
// Ball query: one wave per query. Ordered compaction of first 32 in-radius
// indices (== reference's where->sort->truncate), pad with first index.
// ---------------------------------------------------------------------------
__global__ __launch_bounds__(256) void ballq_kernel(const float* __restrict__ xyz,
                                                    const float* __restrict__ new_xyz,
                                                    int* __restrict__ idx_out) {
    int q    = blockIdx.x * 4 + (threadIdx.x >> 6);
    int lane = threadIdx.x & 63;
    int b    = q >> 11;                        // q / SS
    const float* x = xyz + b * NN * 3;
    const float* c = new_xyz + q * 3;
    float cx = c[0], cy = c[1], cz = c[2];
    int* out = idx_out + q * KK;
    const float R2 = (float)(0.2 * 0.2);       // match reference double->f32 cast

    int count = 0;
    int first = -1;
    for (int base = 0; base < NN; base += 64) {
        int p = base + lane;
        float dx = __fsub_rn(x[p * 3 + 0], cx);
        float dy = __fsub_rn(x[p * 3 + 1], cy);
        float dz = __fsub_rn(x[p * 3 + 2], cz);
        float d  = __fadd_rn(__fadd_rn(__fmul_rn(dx, dx), __fmul_rn(dy, dy)),
                             __fmul_rn(dz, dz));
        bool in = !(d > R2);
        unsigned long long m = __ballot(in);
        if (first < 0 && m != 0ull) first = base + __ffsll((unsigned long long)m) - 1;
        int pre = __popcll(m & ((1ull << lane) - 1ull));
        int pos = count + pre;
        if (in && pos < KK) out[pos] = p;
        count += __popcll(m);
        if (count >= KK) break;                 // wave-uniform
    }
    for (int i2 = count + lane; i2 < KK; i2 += 64) out[i2] = first;
}

// ---------------------------------------------------------------------------
// MLP helpers (thread-per-point recompute chain; weights via uniform s_loads)
// ---------------------------------------------------------------------------
__device__ __forceinline__ void load_in6(const float* __restrict__ xyz,
                                         const float* __restrict__ points,
                                         const float* __restrict__ new_xyz,
                                         const int* __restrict__ idx, int p, float inx[6]) {
    int bs = p >> 5;
    int b  = bs >> 11;
    int pt = idx[p];
    const float* xb = xyz + ((long)b * NN + pt) * 3;
    const float* pb = points + ((long)b * NN + pt) * 3;
    const float* nx = new_xyz + bs * 3;
    inx[0] = xb[0] - nx[0];
    inx[1] = xb[1] - nx[1];
    inx[2] = xb[2] - nx[2];
    inx[3] = pb[0];
    inx[4] = pb[1];
    inx[5] = pb[2];
}

template <int CIN, int COUT>
__device__ __forceinline__ void linear(const float* __restrict__ w,
                                       const float* __restrict__ bias,
                                       const float* xin, float* yout) {
#pragma unroll
    for (int o = 0; o < COUT; o++) {
        float acc = bias[o];
#pragma unroll
        for (int j = 0; j < CIN; j++) acc = fmaf(w[o * CIN + j], xin[j], acc);
        yout[o] = acc;
    }
}

// compute per-channel BN scale/shift from raw sums (threads 0..C-1)
template <int C>
__device__ __forceinline__ void bn_coef(const float* __restrict__ stats,
                                        const float* __restrict__ g,
                                        const float* __restrict__ be,
                                        float* s_sc, float* s_sh) {
    int t = threadIdx.x;
    if (t < C) {
        float mean = stats[t] * (1.0f / (float)NP);
        float var  = stats[C + t] * (1.0f / (float)NP) - mean * mean;
        float rstd = 1.0f / sqrtf(var + EPSF);
        float sc = g[t] * rstd;
        s_sc[t] = sc;
        s_sh[t] = be[t] - mean * sc;
    }
    __syncthreads();
}

// block-level channel sums via LDS transpose (33.8KB), one atomic/chan/block
template <int C>
__device__ __forceinline__ void accum_stats(const float* y, float* __restrict__ gstats) {
    __shared__ float buf[256][33];
    int t = threadIdx.x;
#pragma unroll
    for (int h = 0; h < C / 32; h++) {
        __syncthreads();
#pragma unroll
        for (int c = 0; c < 32; c++) buf[t][c] = y[h * 32 + c];
        __syncthreads();
        if (t < 32) {
            float s = 0.f, sq = 0.f;
            for (int r = 0; r < 256; r++) {
                float v = buf[r][t];
                s += v;
                sq = fmaf(v, v, sq);
            }
            atomicAdd(&gstats[h * 32 + t], s);
            atomicAdd(&gstats[C + h * 32 + t], sq);
        }
    }
}

__global__ __launch_bounds__(256) void l0_stats_kernel(
    const float* __restrict__ xyz, const float* __restrict__ points,
    const float* __restrict__ new_xyz, const int* __restrict__ idx,
    const float* __restrict__ w0, const float* __restrict__ b0_,
    float* __restrict__ stats0) {
    int p = blockIdx.x * 256 + threadIdx.x;
    float inx[6];
    load_in6(xyz, points, new_xyz, idx, p, inx);
    float y0[32];
    linear<6, 32>(w0, b0_, inx, y0);
    accum_stats<32>(y0, stats0);
}

__global__ __launch_bounds__(256) void l1_stats_kernel(
    const float* __restrict__ xyz, const float* __restrict__ points,
    const float* __restrict__ new_xyz, const int* __restrict__ idx,
    const float* __restrict__ w0, const float* __restrict__ b0_,
    const float* __restrict__ g0, const float* __restrict__ be0,
    const float* __restrict__ w1, const float* __restrict__ b1_,
    const float* __restrict__ stats0, float* __restrict__ stats1) {
    __shared__ float sc0[32], sh0[32];
    bn_coef<32>(stats0, g0, be0, sc0, sh0);
    int p = blockIdx.x * 256 + threadIdx.x;
    float inx[6];
    load_in6(xyz, points, new_xyz, idx, p, inx);
    float y0[32];
    linear<6, 32>(w0, b0_, inx, y0);
#pragma unroll
    for (int c = 0; c < 32; c++) y0[c] = fmaxf(fmaf(y0[c], sc0[c], sh0[c]), 0.f);
    float y1[32];
    linear<32, 32>(w1, b1_, y0, y1);
    accum_stats<32>(y1, stats1);
}

__global__ __launch_bounds__(256) void l2_stats_kernel(
    const float* __restrict__ xyz, const float* __restrict__ points,
    const float* __restrict__ new_xyz, const int* __restrict__ idx,
    const float* __restrict__ w0, const float* __restrict__ b0_,
    const float* __restrict__ g0, const float* __restrict__ be0,
    const float* __restrict__ w1, const float* __restrict__ b1_,
    const float* __restrict__ g1, const float* __restrict__ be1,
    const float* __restrict__ w2, const float* __restrict__ b2_,
    const float* __restrict__ stats0, const float* __restrict__ stats1,
    float* __restrict__ stats2) {
    __shared__ float sc0[32], sh0[32], sc1[32], sh1[32];
    bn_coef<32>(stats0, g0, be0, sc0, sh0);
    bn_coef<32>(stats1, g1, be1, sc1, sh1);
    int p = blockIdx.x * 256 + threadIdx.x;
    float inx[6];
    load_in6(xyz, points, new_xyz, idx, p, inx);
    float y0[32];
    linear<6, 32>(w0, b0_, inx, y0);
#pragma unroll
    for (int c = 0; c < 32; c++) y0[c] = fmaxf(fmaf(y0[c], sc0[c], sh0[c]), 0.f);
    float y1[32];
    linear<32, 32>(w1, b1_, y0, y1);
#pragma unroll
    for (int c = 0; c < 32; c++) y1[c] = fmaxf(fmaf(y1[c], sc1[c], sh1[c]), 0.f);
    float y2[64];
    linear<32, 64>(w2, b2_, y1, y2);
    accum_stats<64>(y2, stats2);
}

__global__ __launch_bounds__(256) void final_kernel(
    const float* __restrict__ xyz, const float* __restrict__ points,
    const float* __restrict__ new_xyz, const int* __restrict__ idx,
    const float* __restrict__ w0, const float* __restrict__ b0_,
    const float* __restrict__ g0, const float* __restrict__ be0,
    const float* __restrict__ w1, const float* __restrict__ b1_,
    const float* __restrict__ g1, const float* __restrict__ be1,
    const float* __restrict__ w2, const float* __restrict__ b2_,
    const float* __restrict__ g2, const float* __restrict__ be2,
    const float* __restrict__ stats0, const float* __restrict__ stats1,
    const float* __restrict__ stats2, float* __restrict__ out_points) {
    __shared__ float sc0[32], sh0[32], sc1[32], sh1[32], sc2[64], sh2[64];
    bn_coef<32>(stats0, g0, be0, sc0, sh0);
    bn_coef<32>(stats1, g1, be1, sc1, sh1);
    bn_coef<64>(stats2, g2, be2, sc2, sh2);
    int p = blockIdx.x * 256 + threadIdx.x;
    float inx[6];
    load_in6(xyz, points, new_xyz, idx, p, inx);
    float y0[32];
    linear<6, 32>(w0, b0_, inx, y0);
#pragma unroll
    for (int c = 0; c < 32; c++) y0[c] = fmaxf(fmaf(y0[c], sc0[c], sh0[c]), 0.f);
    float y1[32];
    linear<32, 32>(w1, b1_, y0, y1);
#pragma unroll
    for (int c = 0; c < 32; c++) y1[c] = fmaxf(fmaf(y1[c], sc1[c], sh1[c]), 0.f);
    float y2[64];
    linear<32, 64>(w2, b2_, y1, y2);
    // BN + relu + max over k (k == lane&31; butterfly within each 32-lane half)
#pragma unroll
    for (int c = 0; c < 64; c++) {
        float v = fmaxf(fmaf(y2[c], sc2[c], sh2[c]), 0.f);
#pragma unroll
        for (int off = 1; off < 32; off <<= 1)
            v = fmaxf(v, __shfl_xor(v, off));
        y2[c] = v;
    }
    int lane = threadIdx.x & 63;
    if ((lane & 31) == 0) {                     // k == 0 lanes write their (b,s) row
        int bs = p >> 5;
        float4* o = (float4*)(out_points + (long)bs * 64);
#pragma unroll
        for (int c4 = 0; c4 < 16; c4++)
            o[c4] = make_float4(y2[c4 * 4], y2[c4 * 4 + 1], y2[c4 * 4 + 2], y2[c4 * 4 + 3]);
    }
}

// ---------------------------------------------------------------------------
extern "C" void kernel_launch(void* const* d_in, const int* in_sizes, int n_in,
                              void* d_out, int out_size, void* d_ws, size_t ws_size,
                              hipStream_t stream) {
    (void)in_sizes; (void)n_in; (void)out_size; (void)ws_size;
    const float* xyz    = (const float*)d_in[0];
    const float* points = (const float*)d_in[1];
    const float* w0  = (const float*)d_in[2];
    const float* b0_ = (const float*)d_in[3];
    const float* g0  = (const float*)d_in[4];
    const float* be0 = (const float*)d_in[5];
    const float* w1  = (const float*)d_in[6];
    const float* b1_ = (const float*)d_in[7];
    const float* g1  = (const float*)d_in[8];
    const float* be1 = (const float*)d_in[9];
    const float* w2  = (const float*)d_in[10];
    const float* b2_ = (const float*)d_in[11];
    const float* g2  = (const float*)d_in[12];
    const float* be2 = (const float*)d_in[13];

    float* out        = (float*)d_out;
    float* out_newxyz = out;                 // (8,2048,3)
    float* out_points = out + BB * SS * 3;   // (8,2048,64)

    int*   idx    = (int*)d_ws;              // NP ints = 2MB
    float* stats  = (float*)d_ws + NP;
    float* stats0 = stats;                   // 64 floats (sum32+sq32)
    float* stats1 = stats + 64;              // 64 floats
    float* stats2 = stats + 128;             // 128 floats (sum64+sq64)

    hipMemsetAsync(stats, 0, 256 * sizeof(float), stream);

    fps_kernel<<<BB, TT, 0, stream>>>(xyz, out_newxyz);
    ballq_kernel<<<BB * SS / 4, 256, 0, stream>>>(xyz, out_newxyz, idx);
    l0_stats_kernel<<<NP / 256, 256, 0, stream>>>(xyz, points, out_newxyz, idx, w0, b0_, stats0);
    l1_stats_kernel<<<NP / 256, 256, 0, stream>>>(xyz, points, out_newxyz, idx,
                                                  w0, b0_, g0, be0, w1, b1_, stats0, stats1);
    l2_stats_kernel<<<NP / 256, 256, 0, stream>>>(xyz, points, out_newxyz, idx,
                                                  w0, b0_, g0, be0, w1, b1_, g1, be1,
                                                  w2, b2_, stats0, stats1, stats2);
    final_kernel<<<NP / 256, 256, 0, stream>>>(xyz, points, out_newxyz, idx,
                                               w0, b0_, g0, be0, w1, b1_, g1, be1,
                                               w2, b2_, g2, be2, stats0, stats1, stats2,
                                               out_points);
}